// Round 2
// baseline (10086.753 us; speedup 1.0000x reference)
//
#include <hip/hip_runtime.h>
#include <hip/hip_cooperative_groups.h>

namespace cg = cooperative_groups;

#define VOCAB   32000
#define DIM     512
#define HDIM    512
#define BATCH   32
#define TSTEPS  128
#define TOPKN   5
#define BOSTOK  1
#define ALPHA   0.2f
#define G3H     1536

#define NBLK    256
#define NTHR    256
#define GEMMBLK 250      // blocks doing the logits GEMM, 128 cols each (250*128 = 32000)
#define CPB     128
#define KH      256      // K-half staged in LDS at a time
#define H2LD    (KH + 1) // 257: odd stride -> 8 distinct banks for the 8-row GEMM reads

struct alignas(16) SMem {
    float h2h[BATCH][H2LD];       // 32*257*4 = 32,896 B  (half-K h2 tile)
    float sx[DIM];                // 2,048
    float dd[3][64];              // 768
    float mbv[4][BATCH][TOPKN];   // 2,560  (per-wave topk partials)
    int   mbi[4][BATCH][TOPKN];   // 2,560
    float mrgv[4];                // global-merge scratch
    int   mrgi[4];
    int   mrgt[4];
};                                // ~40.9 KB total

__device__ __forceinline__ bool better(float v1, int i1, float v2, int i2) {
    // jax.lax.top_k order: value desc, index asc on ties
    return (v1 > v2) || (v1 == v2 && i1 < i2);
}

__device__ __forceinline__ void ins5(float (&lv)[TOPKN], int (&li)[TOPKN], float v, int i) {
    if (better(v, i, lv[4], li[4])) {
        lv[4] = v; li[4] = i;
#pragma unroll
        for (int q = 4; q > 0; --q) {
            if (better(lv[q], li[q], lv[q - 1], li[q - 1])) {
                float tv = lv[q]; lv[q] = lv[q - 1]; lv[q - 1] = tv;
                int   ti = li[q]; li[q] = li[q - 1]; li[q - 1] = ti;
            }
        }
    }
}

// acc += sum_{k=0..255} sv[k] * M[(kb+k)*G3H + c]   (ping-pong prefetch of 32)
__device__ __forceinline__ float dot256(const float* __restrict__ M, const float* sv,
                                        int c, int kb, float acc) {
    const float* p = M + (size_t)kb * G3H + c;
    float wa[32], wb[32];
#pragma unroll
    for (int u = 0; u < 32; ++u) wa[u] = p[(size_t)u * G3H];
    for (int k0 = 0; k0 < KH; k0 += 64) {
#pragma unroll
        for (int u = 0; u < 32; ++u) wb[u] = p[(size_t)(k0 + 32 + u) * G3H];
#pragma unroll
        for (int u = 0; u < 32; ++u) acc = fmaf(sv[k0 + u], wa[u], acc);
        if (k0 + 64 < KH) {
#pragma unroll
            for (int u = 0; u < 32; ++u) wa[u] = p[(size_t)(k0 + 64 + u) * G3H];
        }
#pragma unroll
        for (int u = 0; u < 32; ++u) acc = fmaf(sv[k0 + 32 + u], wb[u], acc);
    }
    return acc;
}

// stage src[32][512] cols [kb, kb+256) into s.h2h
__device__ __forceinline__ void stage_half(SMem& s, const float* __restrict__ src,
                                           int kb, int tid) {
#pragma unroll
    for (int it = 0; it < 8; ++it) {
        const int i  = tid + it * NTHR;    // 0..2047
        const int bb = i >> 6;             // 64 float4 per 256-col row
        const int k4 = i & 63;
        const float4 v = *(const float4*)(src + (size_t)bb * DIM + kb + k4 * 4);
        float* d = &s.h2h[bb][k4 * 4];
        d[0] = v.x; d[1] = v.y; d[2] = v.z; d[3] = v.w;
    }
}

__device__ __forceinline__ void loadg(float4 (&wv)[8], float (&av)[8][4],
                                      const float* __restrict__ wp, const SMem& s,
                                      int bg, int kb, int k0) {
#pragma unroll
    for (int u = 0; u < 8; ++u) {
        wv[u] = *(const float4*)(wp + (size_t)(kb + k0 + u) * VOCAB);
#pragma unroll
        for (int bi = 0; bi < 4; ++bi)
            av[u][bi] = s.h2h[bg * 4 + bi][k0 + u];
    }
}

__device__ __forceinline__ void fmacg(float (&acc)[4][4], const float4 (&wv)[8],
                                      const float (&av)[8][4]) {
#pragma unroll
    for (int u = 0; u < 8; ++u) {
#pragma unroll
        for (int bi = 0; bi < 4; ++bi) {
            const float a = av[u][bi];
            acc[bi][0] = fmaf(a, wv[u].x, acc[bi][0]);
            acc[bi][1] = fmaf(a, wv[u].y, acc[bi][1]);
            acc[bi][2] = fmaf(a, wv[u].z, acc[bi][2]);
            acc[bi][3] = fmaf(a, wv[u].w, acc[bi][3]);
        }
    }
}

// hg = h @ U + b_r for this block's 192 entries, K-split via LDS halves of hsrc
__device__ __forceinline__ void prologue_hg(SMem& s, int j, int tid,
                                            const float* __restrict__ U,
                                            const float* __restrict__ b_r,
                                            const float* __restrict__ hsrc,
                                            float* __restrict__ hg) {
    const int g  = j * 192 + tid;
    const int bb = (tid < 192) ? (g / G3H) : 0;
    const int c  = (tid < 192) ? (g - bb * G3H) : 0;
    float hacc = (tid < 192) ? b_r[c] : 0.f;
    for (int half = 0; half < 2; ++half) {
        const int kb = half * KH;
        __syncthreads();
        stage_half(s, hsrc, kb, tid);
        __syncthreads();
        if (tid < 192) hacc = dot256(U, s.h2h[bb], c, kb, hacc);
    }
    if (tid < 192) hg[g] = hacc;
}

// ---------------- Phase A: logits GEMM + topk partials + hg_{t+1} ----------------
__device__ __forceinline__ void phaseA(SMem& s, int j, int tid, int t,
    const float* __restrict__ U,  const float* __restrict__ b_r,
    const float* __restrict__ Wo, const float* __restrict__ bo,
    const float* __restrict__ hsrc, float* __restrict__ out,
    float* __restrict__ hg, float* __restrict__ pval, int* __restrict__ pidx)
{
    const int w   = tid >> 6;
    const int l   = tid & 63;
    const int bg  = l >> 3;
    const int cg2 = l & 7;
    const int cbase = j * CPB + w * 32 + cg2 * 4;
    const bool gemmer = (j < GEMMBLK);

    const int g     = j * 192 + tid;
    const int hb_bb = (tid < 192) ? (g / G3H) : 0;
    const int hb_c  = (tid < 192) ? (g - hb_bb * G3H) : 0;
    float hacc = (tid < 192) ? b_r[hb_c] : 0.f;

    float acc[4][4] = {};

    for (int half = 0; half < 2; ++half) {
        const int kb = half * KH;
        __syncthreads();
        stage_half(s, hsrc, kb, tid);
        __syncthreads();
        if (gemmer) {
            const float* wp = Wo + cbase;
            float4 wva[8], wvb[8];
            float  ava[8][4], avb[8][4];
            loadg(wva, ava, wp, s, bg, kb, 0);
            for (int k0 = 0; k0 < KH; k0 += 16) {
                loadg(wvb, avb, wp, s, bg, kb, k0 + 8);
                fmacg(acc, wva, ava);
                if (k0 + 16 < KH) loadg(wva, ava, wp, s, bg, kb, k0 + 16);
                fmacg(acc, wvb, avb);
            }
        }
        if (tid < 192) hacc = dot256(U, s.h2h[hb_bb], hb_c, kb, hacc);
    }

    if (tid < 192) hg[g] = hacc;

    if (gemmer) {
        const float4 bov = *(const float4*)(bo + cbase);
#pragma unroll
        for (int bi = 0; bi < 4; ++bi) {
            const int bb = bg * 4 + bi;
            float4 v;
            v.x = acc[bi][0] + bov.x;
            v.y = acc[bi][1] + bov.y;
            v.z = acc[bi][2] + bov.z;
            v.w = acc[bi][3] + bov.w;
            *(float4*)(out + ((size_t)bb * TSTEPS + t) * VOCAB + cbase) = v;

            float lv[TOPKN]; int li[TOPKN];
#pragma unroll
            for (int q = 0; q < TOPKN; ++q) { lv[q] = -INFINITY; li[q] = 0x7fffffff; }
            ins5(lv, li, v.x, cbase + 0);
            ins5(lv, li, v.y, cbase + 1);
            ins5(lv, li, v.z, cbase + 2);
            ins5(lv, li, v.w, cbase + 3);
#pragma unroll
            for (int mask = 1; mask < 8; mask <<= 1) {
                float ov[TOPKN]; int oi[TOPKN];
#pragma unroll
                for (int q = 0; q < TOPKN; ++q) {
                    ov[q] = __shfl_xor(lv[q], mask);
                    oi[q] = __shfl_xor(li[q], mask);
                }
#pragma unroll
                for (int q = 0; q < TOPKN; ++q) ins5(lv, li, ov[q], oi[q]);
            }
            if (cg2 == 0) {
#pragma unroll
                for (int q = 0; q < TOPKN; ++q) { s.mbv[w][bb][q] = lv[q]; s.mbi[w][bb][q] = li[q]; }
            }
        }
    }
    __syncthreads();
    if (gemmer && tid < BATCH) {
        float lv[TOPKN]; int li[TOPKN];
#pragma unroll
        for (int q = 0; q < TOPKN; ++q) { lv[q] = -INFINITY; li[q] = 0x7fffffff; }
#pragma unroll
        for (int w4 = 0; w4 < 4; ++w4)
#pragma unroll
            for (int q = 0; q < TOPKN; ++q)
                ins5(lv, li, s.mbv[w4][tid][q], s.mbi[w4][tid][q]);
        const size_t base = ((size_t)tid * NBLK + j) * TOPKN;
#pragma unroll
        for (int q = 0; q < TOPKN; ++q) { pval[base + q] = lv[q]; pidx[base + q] = li[q]; }
    }
}

// ---------------- Phase B: token select + gates -> h2_t ----------------
__device__ __forceinline__ void phaseB(SMem& s, int j, int tid, int t,
    const float* __restrict__ E,   const float* __restrict__ Wx,
    const float* __restrict__ b_i, const int* __restrict__ rix,
    const float* __restrict__ hg,  const float* __restrict__ pval,
    const int* __restrict__ pidx,  const float* __restrict__ hcur,
    float* __restrict__ hnxt)
{
    const int bat = j >> 3;
    const int jj  = (j & 7) * 64;
    int sel = BOSTOK;
    if (t > 0) {
        float lv[TOPKN]; int li[TOPKN];
        if (tid < GEMMBLK) {
            const size_t base = ((size_t)bat * NBLK + tid) * TOPKN;
#pragma unroll
            for (int q = 0; q < TOPKN; ++q) { lv[q] = pval[base + q]; li[q] = pidx[base + q]; }
        } else {
#pragma unroll
            for (int q = 0; q < TOPKN; ++q) { lv[q] = -INFINITY; li[q] = 0x7fffffff; }
        }
        const int ridx = rix[(t - 1) * BATCH + bat];
        for (int r = 0; r < TOPKN; ++r) {
            float cv = lv[0]; int ci = li[0]; int ct = tid;
#pragma unroll
            for (int mask = 1; mask < 64; mask <<= 1) {
                const float ov = __shfl_xor(cv, mask);
                const int   oi = __shfl_xor(ci, mask);
                const int   ot = __shfl_xor(ct, mask);
                if (better(ov, oi, cv, ci)) { cv = ov; ci = oi; ct = ot; }
            }
            if ((tid & 63) == 0) { s.mrgv[tid >> 6] = cv; s.mrgi[tid >> 6] = ci; s.mrgt[tid >> 6] = ct; }
            __syncthreads();
            float bv = s.mrgv[0]; int bi_ = s.mrgi[0]; int bt = s.mrgt[0];
#pragma unroll
            for (int wq = 1; wq < 4; ++wq)
                if (better(s.mrgv[wq], s.mrgi[wq], bv, bi_)) { bv = s.mrgv[wq]; bi_ = s.mrgi[wq]; bt = s.mrgt[wq]; }
            if (r == ridx) sel = bi_;
            __syncthreads();
            if (tid == bt) {   // winner pops its head (static shifts only)
                lv[0]=lv[1]; li[0]=li[1]; lv[1]=lv[2]; li[1]=li[2];
                lv[2]=lv[3]; li[2]=li[3]; lv[3]=lv[4]; li[3]=li[4];
                lv[4] = -INFINITY; li[4] = 0x7fffffff;
            }
        }
    }
    // x = leaky_relu(E[sel])
    for (int i = tid; i < DIM; i += NTHR) {
        const float e = E[(size_t)sel * DIM + i];
        s.sx[i] = e > 0.f ? e : ALPHA * e;
    }
    __syncthreads();
    if (tid < 192) {
        const int o = tid & 63, part = tid >> 6;
        const int c = jj + o + part * HDIM;
        float a = b_i[c];
        a = dot256(Wx, s.sx, c, 0, a);
        a = dot256(Wx, s.sx + KH, c, KH, a);
        s.dd[part][o] = a;
    }
    __syncthreads();
    if (tid < 64) {
        const int c = jj + tid;
        const float xz = s.dd[0][tid], xr = s.dd[1][tid], xh = s.dd[2][tid];
        const float* hgb = hg + (size_t)bat * G3H;
        const float hz = hgb[c], hr = hgb[c + HDIM], hh = hgb[c + 2 * HDIM];
        const float z    = 1.f / (1.f + expf(-(xz + hz)));
        const float r    = 1.f / (1.f + expf(-(xr + hr)));
        const float cand = tanhf(xh + r * hh);
        const float hold = hcur[bat * HDIM + c];
        hnxt[bat * HDIM + c] = z * hold + (1.f - z) * cand;
    }
}

// ---------------- cooperative single-kernel path ----------------
static __global__ void __launch_bounds__(NTHR, 1)
gru_coop(const float* __restrict__ E,  const float* __restrict__ Wx,
         const float* __restrict__ U,  const float* __restrict__ b_i,
         const float* __restrict__ b_r,const float* __restrict__ Wo,
         const float* __restrict__ bo, const float* __restrict__ ctx,
         const int* __restrict__ rix,  float* __restrict__ out,
         float* __restrict__ hbuf,     float* __restrict__ hg,
         float* __restrict__ pval,     int* __restrict__ pidx)
{
    cg::grid_group grid = cg::this_grid();
    const int j = blockIdx.x, tid = threadIdx.x;
    __shared__ SMem s;
    {
        const int g1 = j * NTHR + tid;
        if (g1 < (BATCH * HDIM) / 4) ((float4*)hbuf)[g1] = ((const float4*)ctx)[g1];
    }
    prologue_hg(s, j, tid, U, b_r, ctx, hg);
    grid.sync();
    for (int t = 0; t < TSTEPS; ++t) {
        const int p = t & 1;
        const float* hcur = hbuf + p * (BATCH * HDIM);
        float*       hnxt = hbuf + (p ^ 1) * (BATCH * HDIM);
        phaseB(s, j, tid, t, E, Wx, b_i, rix, hg, pval, pidx, hcur, hnxt);
        grid.sync();
        phaseA(s, j, tid, t, U, b_r, Wo, bo, hnxt, out, hg, pval, pidx);
        grid.sync();
    }
}

// ---------------- non-cooperative fallback path ----------------
static __global__ void __launch_bounds__(NTHR, 1)
k_prologue(const float* __restrict__ U, const float* __restrict__ b_r,
           const float* __restrict__ ctx, float* __restrict__ hbuf,
           float* __restrict__ hg)
{
    __shared__ SMem s;
    const int j = blockIdx.x, tid = threadIdx.x;
    const int g1 = j * NTHR + tid;
    if (g1 < (BATCH * HDIM) / 4) ((float4*)hbuf)[g1] = ((const float4*)ctx)[g1];
    prologue_hg(s, j, tid, U, b_r, ctx, hg);
}

static __global__ void __launch_bounds__(NTHR, 1)
k_phaseB(int t, const float* __restrict__ E, const float* __restrict__ Wx,
         const float* __restrict__ b_i, const int* __restrict__ rix,
         const float* __restrict__ hg, const float* __restrict__ pval,
         const int* __restrict__ pidx, float* __restrict__ hbuf)
{
    __shared__ SMem s;
    const int p = t & 1;
    phaseB(s, blockIdx.x, threadIdx.x, t, E, Wx, b_i, rix, hg, pval, pidx,
           hbuf + p * (BATCH * HDIM), hbuf + (p ^ 1) * (BATCH * HDIM));
}

static __global__ void __launch_bounds__(NTHR, 1)
k_phaseA(int t, const float* __restrict__ U, const float* __restrict__ b_r,
         const float* __restrict__ Wo, const float* __restrict__ bo,
         const float* __restrict__ hbuf, float* __restrict__ out,
         float* __restrict__ hg, float* __restrict__ pval, int* __restrict__ pidx)
{
    __shared__ SMem s;
    const int p = t & 1;
    phaseA(s, blockIdx.x, threadIdx.x, t, U, b_r, Wo, bo,
           hbuf + (p ^ 1) * (BATCH * HDIM), out, hg, pval, pidx);
}

extern "C" void kernel_launch(void* const* d_in, const int* in_sizes, int n_in,
                              void* d_out, int out_size, void* d_ws, size_t ws_size,
                              hipStream_t stream) {
    (void)in_sizes; (void)n_in; (void)out_size; (void)ws_size;
    const float* E   = (const float*)d_in[0];
    const float* Wx  = (const float*)d_in[1];
    const float* U   = (const float*)d_in[2];
    const float* b_i = (const float*)d_in[3];
    const float* b_r = (const float*)d_in[4];
    const float* Wo  = (const float*)d_in[5];
    const float* bo  = (const float*)d_in[6];
    const float* ctx = (const float*)d_in[7];
    const int*   rix = (const int*)d_in[8];
    float* out = (float*)d_out;

    float* ws   = (float*)d_ws;
    float* hbuf = ws;                    // 2*32*512  = 32768 floats
    float* hg   = ws + 32768;            // 32*1536   = 49152 floats
    float* pval = ws + 81920;            // 32*256*5  = 40960 floats
    int*   pidx = (int*)(ws + 122880);   // 32*256*5  = 40960 ints
    // total 640 KiB of d_ws

    // Gate the cooperative path on runtime-visible capability + occupancy.
    int dev = 0;
    (void)hipGetDevice(&dev);
    int coopAttr = 0, numCU = 0, maxBlk = 0;
    (void)hipDeviceGetAttribute(&coopAttr, hipDeviceAttributeCooperativeLaunch, dev);
    (void)hipDeviceGetAttribute(&numCU, hipDeviceAttributeMultiprocessorCount, dev);
    (void)hipOccupancyMaxActiveBlocksPerMultiprocessor(&maxBlk, gru_coop, NTHR, 0);

    bool coop_done = false;
    if (coopAttr && maxBlk >= 1 && (long)maxBlk * numCU >= NBLK) {
        void* args[] = {&E, &Wx, &U, &b_i, &b_r, &Wo, &bo, &ctx, &rix,
                        &out, &hbuf, &hg, &pval, &pidx};
        hipError_t e = hipLaunchCooperativeKernel(gru_coop, dim3(NBLK), dim3(NTHR),
                                                  args, 0u, stream);
        if (e == hipSuccess) coop_done = true;
        else (void)hipGetLastError();   // clear sticky error, fall back
    }
    if (!coop_done) {
        k_prologue<<<dim3(NBLK), dim3(NTHR), 0, stream>>>(U, b_r, ctx, hbuf, hg);
        for (int t = 0; t < TSTEPS; ++t) {
            k_phaseB<<<dim3(NBLK), dim3(NTHR), 0, stream>>>(t, E, Wx, b_i, rix,
                                                            hg, pval, pidx, hbuf);
            k_phaseA<<<dim3(NBLK), dim3(NTHR), 0, stream>>>(t, U, b_r, Wo, bo,
                                                            hbuf, out, hg, pval, pidx);
        }
    }
}